// Round 14
// baseline (1374.597 us; speedup 1.0000x reference)
//
#include <hip/hip_runtime.h>
#include <hip/hip_bf16.h>

// 3-layer stacked LSTM forward (eval). Round 14 = r13 + all-4-gates scans.
//  r13 diagnosis: scan1 limiter = LDS pipe (8 waves x 16 ds_read_b128 = 128
//  DS-insts/CU/step x ~12cyc = 1536 cyc; measured 1762). Fix: r5's topology
//  (thread owns ALL 4 gate rows of one unit) cuts DS insts 4x (2 waves x 16)
//  and kills the gate-exchange barrier. r5 failed only because its 256-VGPR
//  weight array spilled; r13 PROVED the fix (waves_per_eu pin + in-loop "+v"
//  asm makes weights loop-carried/unreloadable -> VGPR 44->88, resident).
//   - scan1: 256 blk x 128 thr (2 waves), w[4][16] uint4 = 256 VGPR pinned,
//     waves_per_eu(1,1) (512-VGPR budget), 1 barrier/step.
//   - scan2: 256 blk x 64 thr (1 wave), w[4][8] = 128 VGPR pinned, NO barriers.
//   - gemm_mfma / gemm_xg3b / scan3 / cvt: unchanged from r13.
// T=512, B=256, IN=97(pad128), H1=128, H2=64, H3=1.

#define T_TOT 512
#define BB    256
#define CH    128
#define NCH   4

typedef __attribute__((ext_vector_type(8))) short  short8v;   // 8 bf16
typedef __attribute__((ext_vector_type(4))) float  float4v;   // MFMA acc

// D += S0.bf16lo*S1.bf16lo + S0.bf16hi*S1.bf16hi  (VOP3P, verified r5/r6)
#define DOT2BF(acc, wu, hu) \
    asm("v_dot2_f32_bf16 %0, %1, %2, %0" : "+v"(acc) : "v"(wu), "v"(hu))

__device__ __forceinline__ float sigm(float x) {
    float e = __expf(-x);
    return __builtin_amdgcn_rcpf(1.0f + e);
}
__device__ __forceinline__ float tanh_(float x) {
    float e = __expf(2.0f * x);
    return 1.0f - 2.0f * __builtin_amdgcn_rcpf(1.0f + e);
}
__device__ __forceinline__ unsigned short f2bf(float x) {
    __hip_bfloat16 b = __float2bfloat16(x);
    return __builtin_bit_cast(unsigned short, b);
}
__device__ __forceinline__ float b2f(unsigned short u) {
    unsigned int x = (unsigned int)u << 16;
    return __builtin_bit_cast(float, x);
}

// ---------------------------------------------------------------------------
__global__ __launch_bounds__(256) void cvt_pad(
    const float* __restrict__ in, __hip_bfloat16* __restrict__ out, int R, int K)
{
    int total = R * 128;
    for (int idx = blockIdx.x * 256 + threadIdx.x; idx < total; idx += gridDim.x * 256) {
        int r = idx >> 7, c = idx & 127;
        float v = (c < K) ? in[(size_t)r * K + c] : 0.0f;
        out[idx] = __float2bfloat16(v);
    }
}
__global__ __launch_bounds__(256) void cvt_plain(
    const float* __restrict__ in, __hip_bfloat16* __restrict__ out, int n)
{
    int i = blockIdx.x * 256 + threadIdx.x;
    if (i < n) out[i] = __float2bfloat16(in[i]);
}
__global__ __launch_bounds__(256) void addvec(
    const float* __restrict__ a, const float* __restrict__ b, float* __restrict__ o, int n)
{
    int i = blockIdx.x * 256 + threadIdx.x;
    if (i < n) o[i] = a[i] + b[i];
}

// ---------------------------------------------------------------------------
// bf16 MFMA GEMM (r4, verified): C[M,N] = A[M,128] * W[N,128]^T + bias
// ---------------------------------------------------------------------------
__global__ __launch_bounds__(256) void gemm_mfma(
    const __hip_bfloat16* __restrict__ A,
    const __hip_bfloat16* __restrict__ W,
    const float* __restrict__ bias,
    float* __restrict__ C, int N)
{
    __shared__ __hip_bfloat16 At[128 * 128];   // 32 KB

    const int tid  = threadIdx.x;
    const int lane = tid & 63;
    const int wid  = tid >> 6;
    const int m0   = blockIdx.x * 128;
    const int n0   = blockIdx.y * 128;
    const int wr   = wid >> 1;
    const int wc   = wid & 1;

    short8v bfrag[4][4];  // [nf][kf]
    {
        const char* Wg = (const char*)W;
#pragma unroll
        for (int nf = 0; nf < 4; ++nf) {
            int row = n0 + wc * 64 + nf * 16 + (lane & 15);
#pragma unroll
            for (int kf = 0; kf < 4; ++kf) {
                int colb = (kf * 32 + (lane >> 4) * 8) * 2;
                bfrag[nf][kf] = *(const short8v*)(Wg + (size_t)row * 256 + colb);
            }
        }
    }
    {
        const char* Ag = (const char*)(A + (size_t)m0 * 128);
        char* As = (char*)At;
#pragma unroll
        for (int r2 = 0; r2 < 8; ++r2) {
            int off = r2 * 4096 + tid * 16;
            int row = off >> 8;
            int bir = off & 255;
            short8v v = *(const short8v*)(Ag + (size_t)row * 256 + bir);
            int sw = bir ^ ((row & 7) << 4);
            *(short8v*)(As + row * 256 + sw) = v;
        }
    }
    __syncthreads();

    float4v acc[4][4] = {};
#pragma unroll
    for (int kf = 0; kf < 4; ++kf) {
        short8v af[4];
#pragma unroll
        for (int mf = 0; mf < 4; ++mf) {
            int row   = wr * 64 + mf * 16 + (lane & 15);
            int kbyte = kf * 64 + (lane >> 4) * 16;
            int sw    = kbyte ^ ((row & 7) << 4);
            af[mf] = *(const short8v*)((const char*)At + row * 256 + sw);
        }
#pragma unroll
        for (int mf = 0; mf < 4; ++mf)
#pragma unroll
            for (int nf = 0; nf < 4; ++nf)
                acc[mf][nf] = __builtin_amdgcn_mfma_f32_16x16x32_bf16(
                    af[mf], bfrag[nf][kf], acc[mf][nf], 0, 0, 0);
    }

#pragma unroll
    for (int nf = 0; nf < 4; ++nf) {
        int col = n0 + wc * 64 + nf * 16 + (lane & 15);
        float bv = bias[col];
#pragma unroll
        for (int mf = 0; mf < 4; ++mf) {
            int rbase = m0 + wr * 64 + mf * 16 + (lane >> 4) * 4;
#pragma unroll
            for (int r = 0; r < 4; ++r)
                C[(size_t)(rbase + r) * N + col] = acc[mf][nf][r] + bv;
        }
    }
}

// ---------------------------------------------------------------------------
// scan1 (H=128): 256 blocks x 128 thr (2 waves). Thread n owns unit n: gate
// rows {n, n+128, n+256, n+384} = 4 x 128 bf16 = 64 uint4 = 256 VGPR, held
// resident by waves_per_eu(1,1) (512-VGPR budget) + in-loop "+v" pin
// (loop-carried, unreloadable - r13-verified). h bf16 in LDS, broadcast
// b128 reads: 32 DS-insts/CU/step (vs 128 in r13). ONE barrier/step.
// ---------------------------------------------------------------------------
__global__ __launch_bounds__(128)
__attribute__((amdgpu_waves_per_eu(1, 1)))
void lstm_scan1(
    const float* __restrict__ xg,        // [Tc, BB, 512] f32, bias included
    const unsigned int* __restrict__ Wp, // [512 rows][64 uint] bf16-pairs
    __hip_bfloat16* __restrict__ hout,   // [Tc, BB, 128]
    float* __restrict__ hstate, float* __restrict__ cstate,
    int Tc, int first)
{
    const int n   = threadIdx.x;     // unit 0..127
    const int row = blockIdx.x;
    __shared__ unsigned int hbuf[2][64];   // 128 bf16, double-buffered

    uint4 w[4][16];   // 256 VGPR of weights, static-indexed
#pragma unroll
    for (int G = 0; G < 4; ++G) {
        const uint4* wr_ = (const uint4*)(Wp + (size_t)(G * 128 + n) * 64);
#pragma unroll
        for (int j = 0; j < 16; ++j) w[G][j] = wr_[j];
    }

    float c  = first ? 0.0f : cstate[row * 128 + n];
    float hf = first ? 0.0f : hstate[row * 128 + n];
    ((unsigned short*)hbuf[0])[n] = f2bf(hf);
    __syncthreads();

    const float* px = xg + (size_t)row * 512 + n;
    float xc0 = px[0],   xc1 = px[128], xc2 = px[256], xc3 = px[384];
    float xn0 = 0, xn1 = 0, xn2 = 0, xn3 = 0;
    if (Tc > 1) { const float* q = px + (size_t)BB * 512;
                  xn0 = q[0]; xn1 = q[128]; xn2 = q[256]; xn3 = q[384]; }

    int cur = 0;
    for (int t = 0; t < Tc; ++t) {
        // In-loop pin: weights loop-carried through opaque asm -> loads
        // cannot be sunk/rematerialized in-loop (r13-verified mechanism).
#pragma unroll
        for (int G = 0; G < 4; ++G)
#pragma unroll
            for (int j = 0; j < 16; ++j)
                asm volatile("" : "+v"(w[G][j].x), "+v"(w[G][j].y),
                                  "+v"(w[G][j].z), "+v"(w[G][j].w));

        float a0 = xc0, a1 = xc1, a2 = xc2, a3 = xc3;
        xc0 = xn0; xc1 = xn1; xc2 = xn2; xc3 = xn3;
        if (t + 2 < Tc) {
            const float* q = px + (size_t)(t + 2) * BB * 512;
            xn0 = q[0]; xn1 = q[128]; xn2 = q[256]; xn3 = q[384];
        }

        const uint4* hb = (const uint4*)hbuf[cur];   // wave-uniform broadcast
#pragma unroll
        for (int j = 0; j < 16; ++j) {
            uint4 hv = hb[j];
            DOT2BF(a0, w[0][j].x, hv.x); DOT2BF(a0, w[0][j].y, hv.y);
            DOT2BF(a0, w[0][j].z, hv.z); DOT2BF(a0, w[0][j].w, hv.w);
            DOT2BF(a1, w[1][j].x, hv.x); DOT2BF(a1, w[1][j].y, hv.y);
            DOT2BF(a1, w[1][j].z, hv.z); DOT2BF(a1, w[1][j].w, hv.w);
            DOT2BF(a2, w[2][j].x, hv.x); DOT2BF(a2, w[2][j].y, hv.y);
            DOT2BF(a2, w[2][j].z, hv.z); DOT2BF(a2, w[2][j].w, hv.w);
            DOT2BF(a3, w[3][j].x, hv.x); DOT2BF(a3, w[3][j].y, hv.y);
            DOT2BF(a3, w[3][j].z, hv.z); DOT2BF(a3, w[3][j].w, hv.w);
        }

        float i_ = sigm(a0), f_ = sigm(a1), g_ = tanh_(a2), o_ = sigm(a3);
        c  = fmaf(f_, c, i_ * g_);
        hf = o_ * tanh_(c);
        unsigned short hb16 = f2bf(hf);
        ((unsigned short*)hbuf[cur ^ 1])[n] = hb16;
        ((unsigned short*)hout)[((size_t)t * BB + row) * 128 + n] = hb16;
        cur ^= 1;
        __syncthreads();
    }
    cstate[row * 128 + n] = c;
    hstate[row * 128 + n] = hf;
}

// ---------------------------------------------------------------------------
// scan2 (H=64): 256 blocks x 64 thr = ONE wave -> no barriers (in-wave lgkm
// ordering). Thread n owns unit n: 4 x 64 bf16 = 32 uint4 = 128 VGPR, pinned.
// h2 output bf16 (feeds bf16 layer-3 GEMM).
// ---------------------------------------------------------------------------
__global__ __launch_bounds__(64)
__attribute__((amdgpu_waves_per_eu(1, 1)))
void lstm_scan2(
    const float* __restrict__ xg,        // [Tc, BB, 256]
    const unsigned int* __restrict__ Wp, // [256 rows][32 uint] bf16-pairs
    __hip_bfloat16* __restrict__ hout,   // [Tc, BB, 64] bf16
    float* __restrict__ hstate, float* __restrict__ cstate,
    int Tc, int first)
{
    const int n   = threadIdx.x;   // unit 0..63
    const int row = blockIdx.x;
    __shared__ unsigned int hbuf[2][32];

    uint4 w[4][8];   // 128 VGPR
#pragma unroll
    for (int G = 0; G < 4; ++G) {
        const uint4* wr_ = (const uint4*)(Wp + (size_t)(G * 64 + n) * 32);
#pragma unroll
        for (int j = 0; j < 8; ++j) w[G][j] = wr_[j];
    }

    float c  = first ? 0.0f : cstate[row * 64 + n];
    float hf = first ? 0.0f : hstate[row * 64 + n];
    ((unsigned short*)hbuf[0])[n] = f2bf(hf);

    const float* px = xg + (size_t)row * 256 + n;
    float xc0 = px[0],  xc1 = px[64], xc2 = px[128], xc3 = px[192];
    float xn0 = 0, xn1 = 0, xn2 = 0, xn3 = 0;
    if (Tc > 1) { const float* q = px + (size_t)BB * 256;
                  xn0 = q[0]; xn1 = q[64]; xn2 = q[128]; xn3 = q[192]; }

    int cur = 0;
    for (int t = 0; t < Tc; ++t) {
#pragma unroll
        for (int G = 0; G < 4; ++G)
#pragma unroll
            for (int j = 0; j < 8; ++j)
                asm volatile("" : "+v"(w[G][j].x), "+v"(w[G][j].y),
                                  "+v"(w[G][j].z), "+v"(w[G][j].w));

        float a0 = xc0, a1 = xc1, a2 = xc2, a3 = xc3;
        xc0 = xn0; xc1 = xn1; xc2 = xn2; xc3 = xn3;
        if (t + 2 < Tc) {
            const float* q = px + (size_t)(t + 2) * BB * 256;
            xn0 = q[0]; xn1 = q[64]; xn2 = q[128]; xn3 = q[192];
        }

        const uint4* hb = (const uint4*)hbuf[cur];
#pragma unroll
        for (int j = 0; j < 8; ++j) {
            uint4 hv = hb[j];
            DOT2BF(a0, w[0][j].x, hv.x); DOT2BF(a0, w[0][j].y, hv.y);
            DOT2BF(a0, w[0][j].z, hv.z); DOT2BF(a0, w[0][j].w, hv.w);
            DOT2BF(a1, w[1][j].x, hv.x); DOT2BF(a1, w[1][j].y, hv.y);
            DOT2BF(a1, w[1][j].z, hv.z); DOT2BF(a1, w[1][j].w, hv.w);
            DOT2BF(a2, w[2][j].x, hv.x); DOT2BF(a2, w[2][j].y, hv.y);
            DOT2BF(a2, w[2][j].z, hv.z); DOT2BF(a2, w[2][j].w, hv.w);
            DOT2BF(a3, w[3][j].x, hv.x); DOT2BF(a3, w[3][j].y, hv.y);
            DOT2BF(a3, w[3][j].z, hv.z); DOT2BF(a3, w[3][j].w, hv.w);
        }

        float i_ = sigm(a0), f_ = sigm(a1), g_ = tanh_(a2), o_ = sigm(a3);
        c  = fmaf(f_, c, i_ * g_);
        hf = o_ * tanh_(c);
        unsigned short hb16 = f2bf(hf);
        ((unsigned short*)hbuf[cur ^ 1])[n] = hb16;
        ((unsigned short*)hout)[((size_t)t * BB + row) * 64 + n] = hb16;
        cur ^= 1;
    }
    cstate[row * 64 + n] = c;
    hstate[row * 64 + n] = hf;
}

// ---------------------------------------------------------------------------
// Layer-3 input GEMM, bf16 X: out[m,0..3] = sum_k X[m,k]*W[n,k] + b
// ---------------------------------------------------------------------------
__global__ __launch_bounds__(256) void gemm_xg3b(
    const __hip_bfloat16* __restrict__ X,  // [M, 64] bf16
    const float* __restrict__ W,           // [4, 64] f32
    const float* __restrict__ b1, const float* __restrict__ b2,
    float* __restrict__ out)               // [M, 4]
{
    __shared__ __align__(16) float ws4[4][64];
    __shared__ float bb[4];
    const int tid = threadIdx.x;
    {
        const int nn = tid >> 6, kk = tid & 63;
        ws4[nn][kk] = W[nn * 64 + kk];
    }
    if (tid < 4) bb[tid] = b1[tid] + b2[tid];
    __syncthreads();

    const int m = blockIdx.x * 256 + tid;
    const uint4* xr = reinterpret_cast<const uint4*>(X + (size_t)m * 64);
    float a0 = bb[0], a1 = bb[1], a2 = bb[2], a3 = bb[3];
#pragma unroll
    for (int kk = 0; kk < 8; ++kk) {       // 8 bf16 per uint4
        uint4 v = xr[kk];
        float xf[8];
        xf[0] = b2f((unsigned short)(v.x & 0xffff));
        xf[1] = b2f((unsigned short)(v.x >> 16));
        xf[2] = b2f((unsigned short)(v.y & 0xffff));
        xf[3] = b2f((unsigned short)(v.y >> 16));
        xf[4] = b2f((unsigned short)(v.z & 0xffff));
        xf[5] = b2f((unsigned short)(v.z >> 16));
        xf[6] = b2f((unsigned short)(v.w & 0xffff));
        xf[7] = b2f((unsigned short)(v.w >> 16));
#pragma unroll
        for (int j = 0; j < 8; ++j) {
            int k = kk * 8 + j;
            a0 = fmaf(xf[j], ws4[0][k], a0);
            a1 = fmaf(xf[j], ws4[1][k], a1);
            a2 = fmaf(xf[j], ws4[2][k], a2);
            a3 = fmaf(xf[j], ws4[3][k], a3);
        }
    }
    float4 o; o.x = a0; o.y = a1; o.z = a2; o.w = a3;
    *reinterpret_cast<float4*>(&out[(size_t)m * 4]) = o;
}

// ---------------------------------------------------------------------------
// Layer-3 scan: 8-deep static prefetch ring (r5, verified).
// ---------------------------------------------------------------------------
__global__ __launch_bounds__(256) void lstm_scan3(
    const float* __restrict__ xg,   // [T, B, 4]
    const float* __restrict__ Whh,  // [4, 1]
    float* __restrict__ out,        // [T, B]
    int T)
{
    const int b = threadIdx.x;
    const float w0 = Whh[0], w1 = Whh[1], w2 = Whh[2], w3 = Whh[3];
    float h = 0.0f, c = 0.0f;
    const float4* p = reinterpret_cast<const float4*>(xg) + b;

    float4 cur[8], nxt[8];
#pragma unroll
    for (int j = 0; j < 8; ++j) cur[j] = p[(size_t)j * BB];

    for (int t0 = 0; t0 < T; t0 += 8) {
#pragma unroll
        for (int j = 0; j < 8; ++j) {
            int tt = t0 + 8 + j;
            if (tt < T) nxt[j] = p[(size_t)tt * BB];
        }
#pragma unroll
        for (int j = 0; j < 8; ++j) {
            float4 g4 = cur[j];
            float gi = fmaf(h, w0, g4.x);
            float gf = fmaf(h, w1, g4.y);
            float gg = fmaf(h, w2, g4.z);
            float go = fmaf(h, w3, g4.w);
            float i_ = sigm(gi);
            float f_ = sigm(gf);
            float g_ = tanh_(gg);
            float o_ = sigm(go);
            c = fmaf(f_, c, i_ * g_);
            h = o_ * tanh_(c);
            out[(size_t)(t0 + j) * BB + b] = h;
        }
#pragma unroll
        for (int j = 0; j < 8; ++j) cur[j] = nxt[j];
    }
}

// ---------------------------------------------------------------------------
extern "C" void kernel_launch(void* const* d_in, const int* in_sizes, int n_in,
                              void* d_out, int out_size, void* d_ws, size_t ws_size,
                              hipStream_t stream) {
    const float* x    = (const float*)d_in[0];
    const float* Wih1 = (const float*)d_in[1];
    const float* Whh1 = (const float*)d_in[2];
    const float* bih1 = (const float*)d_in[3];
    const float* bhh1 = (const float*)d_in[4];
    const float* Wih2 = (const float*)d_in[5];
    const float* Whh2 = (const float*)d_in[6];
    const float* bih2 = (const float*)d_in[7];
    const float* bhh2 = (const float*)d_in[8];
    const float* Wih3 = (const float*)d_in[9];
    const float* Whh3 = (const float*)d_in[10];
    const float* bih3 = (const float*)d_in[11];
    const float* bhh3 = (const float*)d_in[12];
    float* out = (float*)d_out;

    char* ws = (char*)d_ws;
    // Workspace layout, ~187.4 MB total:
    float*          xg1c  = (float*)(ws + 0);                   // [CH,B,512] f32 = 67,108,864
    float*          xg2c  = (float*)(ws + 67108864);            // [CH,B,256] f32 = 33,554,432
    __hip_bfloat16* xb    = (__hip_bfloat16*)(ws + 100663296);  // [T,B,128] bf16 = 33,554,432
    __hip_bfloat16* h1b   = (__hip_bfloat16*)(ws + 134217728);  // [T,B,128] bf16 = 33,554,432
    __hip_bfloat16* h2bb  = (__hip_bfloat16*)(ws + 167772160);  // [T,B,64]  bf16 = 16,777,216
    float*          xg3   = (float*)(ws + 184549376);           // [T,B,4]   f32  =  2,097,152
    __hip_bfloat16* wb1   = (__hip_bfloat16*)(ws + 186646528);  // [512,128] =   131,072
    __hip_bfloat16* whb1  = (__hip_bfloat16*)(ws + 186777600);  // [512,128] =   131,072
    __hip_bfloat16* wb2   = (__hip_bfloat16*)(ws + 186908672);  // [256,128] =    65,536
    __hip_bfloat16* whb2  = (__hip_bfloat16*)(ws + 186974208);  // [256,64]  =    32,768
    float*          bias1 = (float*)(ws + 187006976);           //     2,048
    float*          bias2 = (float*)(ws + 187009024);           //     1,024
    float*          bias3 = (float*)(ws + 187010048);           //        64
    float*          st1h  = (float*)(ws + 187010112);           // [B,128] f32
    float*          st1c  = (float*)(ws + 187141184);
    float*          st2h  = (float*)(ws + 187272256);           // [B,64] f32
    float*          st2c  = (float*)(ws + 187337792);

    // ---- P0: conversions / bias prep ----
    cvt_pad<<<4096, 256, 0, stream>>>(x, xb, T_TOT * BB, 97);
    cvt_pad<<<256, 256, 0, stream>>>(Wih1, wb1, 512, 97);
    cvt_plain<<<256, 256, 0, stream>>>(Whh1, whb1, 512 * 128);
    cvt_plain<<<128, 256, 0, stream>>>(Wih2, wb2, 256 * 128);
    cvt_plain<<<64, 256, 0, stream>>>(Whh2, whb2, 256 * 64);
    addvec<<<2, 256, 0, stream>>>(bih1, bhh1, bias1, 512);
    addvec<<<1, 256, 0, stream>>>(bih2, bhh2, bias2, 256);

    // ---- Layer 1 (chunked over T) ----
    for (int c0 = 0; c0 < NCH; ++c0) {
        gemm_mfma<<<dim3(CH * BB / 128, 512 / 128), 256, 0, stream>>>(
            xb + (size_t)c0 * CH * BB * 128, wb1, bias1, xg1c, 512);
        lstm_scan1<<<BB, 128, 0, stream>>>(
            xg1c, (const unsigned int*)whb1,
            h1b + (size_t)c0 * CH * BB * 128, st1h, st1c, CH, c0 == 0);
    }
    // ---- Layer 2 (chunked over T) ----
    for (int c0 = 0; c0 < NCH; ++c0) {
        gemm_mfma<<<dim3(CH * BB / 128, 256 / 128), 256, 0, stream>>>(
            h1b + (size_t)c0 * CH * BB * 128, wb2, bias2, xg2c, 256);
        lstm_scan2<<<BB, 64, 0, stream>>>(
            xg2c, (const unsigned int*)whb2,
            h2bb + (size_t)c0 * CH * BB * 64, st2h, st2c, CH, c0 == 0);
    }
    // ---- Layer 3 ----
    gemm_xg3b<<<T_TOT * BB / 256, 256, 0, stream>>>(h2bb, Wih3, bih3, bhh3, xg3);
    lstm_scan3<<<1, 256, 0, stream>>>(xg3, Whh3, out, T_TOT);
}

// Round 15
// 903.815 us; speedup vs baseline: 1.5209x; 1.5209x over previous
//
#include <hip/hip_runtime.h>
#include <hip/hip_bf16.h>

// 3-layer stacked LSTM forward (eval). Round 15 = r13 (837us best) with scan1
// moved to the 4-wave midpoint of the DS-pipe/latency tradeoff:
//  r13 (8 waves, 1 row/thr): DS=128 insts/CU/step = 1536cyc -> measured 1762 (DS-bound)
//  r14 (2 waves, 4 rows/thr): DS=384cyc but 0.5 waves/SIMD -> latency-bound 3860
//  r15 (4 waves, 2 rows/thr): DS=64 insts=768cyc, 1 wave/SIMD on all SIMDs,
//      weights 2x16 uint4 = 128 VGPR (+~40 ovh) under the 256 budget of
//      waves_per_eu(2,2) -- the exact attr+in-loop-pin combo r13 verified.
//  scan2 / gemm_mfma / gemm_xg3b / scan3 / cvt: byte-identical to r13.
// T=512, B=256, IN=97(pad128), H1=128, H2=64, H3=1.

#define T_TOT 512
#define BB    256
#define CH    128
#define NCH   4

typedef __attribute__((ext_vector_type(8))) short  short8v;   // 8 bf16
typedef __attribute__((ext_vector_type(4))) float  float4v;   // MFMA acc

// D += S0.bf16lo*S1.bf16lo + S0.bf16hi*S1.bf16hi  (VOP3P, verified r5/r6)
#define DOT2BF(acc, wu, hu) \
    asm("v_dot2_f32_bf16 %0, %1, %2, %0" : "+v"(acc) : "v"(wu), "v"(hu))

__device__ __forceinline__ float sigm(float x) {
    float e = __expf(-x);
    return __builtin_amdgcn_rcpf(1.0f + e);
}
__device__ __forceinline__ float tanh_(float x) {
    float e = __expf(2.0f * x);
    return 1.0f - 2.0f * __builtin_amdgcn_rcpf(1.0f + e);
}
__device__ __forceinline__ unsigned short f2bf(float x) {
    __hip_bfloat16 b = __float2bfloat16(x);
    return __builtin_bit_cast(unsigned short, b);
}
__device__ __forceinline__ float b2f(unsigned short u) {
    unsigned int x = (unsigned int)u << 16;
    return __builtin_bit_cast(float, x);
}

// ---------------------------------------------------------------------------
__global__ __launch_bounds__(256) void cvt_pad(
    const float* __restrict__ in, __hip_bfloat16* __restrict__ out, int R, int K)
{
    int total = R * 128;
    for (int idx = blockIdx.x * 256 + threadIdx.x; idx < total; idx += gridDim.x * 256) {
        int r = idx >> 7, c = idx & 127;
        float v = (c < K) ? in[(size_t)r * K + c] : 0.0f;
        out[idx] = __float2bfloat16(v);
    }
}
__global__ __launch_bounds__(256) void cvt_plain(
    const float* __restrict__ in, __hip_bfloat16* __restrict__ out, int n)
{
    int i = blockIdx.x * 256 + threadIdx.x;
    if (i < n) out[i] = __float2bfloat16(in[i]);
}
__global__ __launch_bounds__(256) void addvec(
    const float* __restrict__ a, const float* __restrict__ b, float* __restrict__ o, int n)
{
    int i = blockIdx.x * 256 + threadIdx.x;
    if (i < n) o[i] = a[i] + b[i];
}

// ---------------------------------------------------------------------------
// bf16 MFMA GEMM (r4, verified): C[M,N] = A[M,128] * W[N,128]^T + bias
// ---------------------------------------------------------------------------
__global__ __launch_bounds__(256) void gemm_mfma(
    const __hip_bfloat16* __restrict__ A,
    const __hip_bfloat16* __restrict__ W,
    const float* __restrict__ bias,
    float* __restrict__ C, int N)
{
    __shared__ __hip_bfloat16 At[128 * 128];   // 32 KB

    const int tid  = threadIdx.x;
    const int lane = tid & 63;
    const int wid  = tid >> 6;
    const int m0   = blockIdx.x * 128;
    const int n0   = blockIdx.y * 128;
    const int wr   = wid >> 1;
    const int wc   = wid & 1;

    short8v bfrag[4][4];  // [nf][kf]
    {
        const char* Wg = (const char*)W;
#pragma unroll
        for (int nf = 0; nf < 4; ++nf) {
            int row = n0 + wc * 64 + nf * 16 + (lane & 15);
#pragma unroll
            for (int kf = 0; kf < 4; ++kf) {
                int colb = (kf * 32 + (lane >> 4) * 8) * 2;
                bfrag[nf][kf] = *(const short8v*)(Wg + (size_t)row * 256 + colb);
            }
        }
    }
    {
        const char* Ag = (const char*)(A + (size_t)m0 * 128);
        char* As = (char*)At;
#pragma unroll
        for (int r2 = 0; r2 < 8; ++r2) {
            int off = r2 * 4096 + tid * 16;
            int row = off >> 8;
            int bir = off & 255;
            short8v v = *(const short8v*)(Ag + (size_t)row * 256 + bir);
            int sw = bir ^ ((row & 7) << 4);
            *(short8v*)(As + row * 256 + sw) = v;
        }
    }
    __syncthreads();

    float4v acc[4][4] = {};
#pragma unroll
    for (int kf = 0; kf < 4; ++kf) {
        short8v af[4];
#pragma unroll
        for (int mf = 0; mf < 4; ++mf) {
            int row   = wr * 64 + mf * 16 + (lane & 15);
            int kbyte = kf * 64 + (lane >> 4) * 16;
            int sw    = kbyte ^ ((row & 7) << 4);
            af[mf] = *(const short8v*)((const char*)At + row * 256 + sw);
        }
#pragma unroll
        for (int mf = 0; mf < 4; ++mf)
#pragma unroll
            for (int nf = 0; nf < 4; ++nf)
                acc[mf][nf] = __builtin_amdgcn_mfma_f32_16x16x32_bf16(
                    af[mf], bfrag[nf][kf], acc[mf][nf], 0, 0, 0);
    }

#pragma unroll
    for (int nf = 0; nf < 4; ++nf) {
        int col = n0 + wc * 64 + nf * 16 + (lane & 15);
        float bv = bias[col];
#pragma unroll
        for (int mf = 0; mf < 4; ++mf) {
            int rbase = m0 + wr * 64 + mf * 16 + (lane >> 4) * 4;
#pragma unroll
            for (int r = 0; r < 4; ++r)
                C[(size_t)(rbase + r) * N + col] = acc[mf][nf][r] + bv;
        }
    }
}

// ---------------------------------------------------------------------------
// scan1 (H=128): 256 blocks x 256 thr (4 waves, 1/SIMD). Thread n owns gate
// rows {n, n+256}: 2 x 128 bf16 = 32 uint4 = 128 VGPR, held resident by
// waves_per_eu(2,2) (256-VGPR budget) + in-loop "+v" pin (r13-verified).
// h read ONCE per thread (16 b128, reused for both rows): 64 DS-insts/CU/step.
// Gate exchange via g_lds; 2 barriers/step.
// ---------------------------------------------------------------------------
__global__ __launch_bounds__(256)
__attribute__((amdgpu_waves_per_eu(2, 2)))
void lstm_scan1(
    const float* __restrict__ xg,        // [Tc, BB, 512] f32, bias included
    const unsigned int* __restrict__ Wp, // [512 rows][64 uint] bf16-pairs
    __hip_bfloat16* __restrict__ hout,   // [Tc, BB, 128]
    float* __restrict__ hstate, float* __restrict__ cstate,
    int Tc, int first)
{
    const int n   = threadIdx.x;     // 0..255: owns gate rows n and n+256
    const int row = blockIdx.x;
    __shared__ unsigned int hbuf[2][64];   // 128 bf16, double-buffered
    __shared__ float g_lds[512];

    uint4 w[2][16];   // 128 VGPR of weights, static-indexed
#pragma unroll
    for (int G = 0; G < 2; ++G) {
        const uint4* wr_ = (const uint4*)(Wp + (size_t)(G * 256 + n) * 64);
#pragma unroll
        for (int j = 0; j < 16; ++j) w[G][j] = wr_[j];
    }

    float c = 0.0f, hf = 0.0f;
    if (n < 128) {
        c  = first ? 0.0f : cstate[row * 128 + n];
        hf = first ? 0.0f : hstate[row * 128 + n];
        ((unsigned short*)hbuf[0])[n] = f2bf(hf);
    }
    __syncthreads();

    const float* px = xg + (size_t)row * 512 + n;
    float xcL = px[0],  xcH = px[256];
    float xnL = 0.0f,   xnH = 0.0f;
    if (Tc > 1) { const float* q = px + (size_t)BB * 512; xnL = q[0]; xnH = q[256]; }

    int cur = 0;
    for (int t = 0; t < Tc; ++t) {
        // In-loop pin: weights loop-carried through opaque asm -> loads cannot
        // be sunk/rematerialized in-loop (r13-verified mechanism).
#pragma unroll
        for (int G = 0; G < 2; ++G)
#pragma unroll
            for (int j = 0; j < 16; ++j)
                asm volatile("" : "+v"(w[G][j].x), "+v"(w[G][j].y),
                                  "+v"(w[G][j].z), "+v"(w[G][j].w));

        float aL = xcL, aH = xcH;
        xcL = xnL; xcH = xnH;
        if (t + 2 < Tc) {
            const float* q = px + (size_t)(t + 2) * BB * 512;
            xnL = q[0]; xnH = q[256];
        }

        const uint4* hb = (const uint4*)hbuf[cur];   // wave-uniform broadcast
#pragma unroll
        for (int j = 0; j < 16; ++j) {
            uint4 hv = hb[j];
            DOT2BF(aL, w[0][j].x, hv.x); DOT2BF(aL, w[0][j].y, hv.y);
            DOT2BF(aL, w[0][j].z, hv.z); DOT2BF(aL, w[0][j].w, hv.w);
            DOT2BF(aH, w[1][j].x, hv.x); DOT2BF(aH, w[1][j].y, hv.y);
            DOT2BF(aH, w[1][j].z, hv.z); DOT2BF(aH, w[1][j].w, hv.w);
        }
        g_lds[n]       = aL;
        g_lds[n + 256] = aH;
        __syncthreads();

        if (n < 128) {
            float i_ = sigm(g_lds[n]);
            float f_ = sigm(g_lds[n + 128]);
            float g_ = tanh_(g_lds[n + 256]);
            float o_ = sigm(g_lds[n + 384]);
            c  = fmaf(f_, c, i_ * g_);
            hf = o_ * tanh_(c);
            unsigned short hb16 = f2bf(hf);
            ((unsigned short*)hbuf[cur ^ 1])[n] = hb16;
            ((unsigned short*)hout)[((size_t)t * BB + row) * 128 + n] = hb16;
        }
        cur ^= 1;
        __syncthreads();
    }
    if (n < 128) {
        cstate[row * 128 + n] = c;
        hstate[row * 128 + n] = hf;
    }
}

// ---------------------------------------------------------------------------
// scan2 (H=64): unchanged from r13. 256 blocks x 256 thr, 1 gate-row/thread,
// 8 uint4 = 32 VGPR pinned, waves_per_eu(1,1). h2 output bf16.
// ---------------------------------------------------------------------------
__global__ __launch_bounds__(256)
__attribute__((amdgpu_waves_per_eu(1, 1)))
void lstm_scan2(
    const float* __restrict__ xg,        // [Tc, BB, 256]
    const unsigned int* __restrict__ Wp, // [256 rows][32 uint] bf16-pairs
    __hip_bfloat16* __restrict__ hout,   // [Tc, BB, 64] bf16
    float* __restrict__ hstate, float* __restrict__ cstate,
    int Tc, int first)
{
    const int n   = threadIdx.x;   // gate-row 0..255
    const int row = blockIdx.x;
    __shared__ unsigned int hbuf[2][32];
    __shared__ float g_lds[256];

    uint4 w[8];
    {
        const uint4* wr_ = (const uint4*)(Wp + (size_t)n * 32);
#pragma unroll
        for (int j = 0; j < 8; ++j) w[j] = wr_[j];
    }

    float c = 0.0f, hf = 0.0f;
    if (n < 64) {
        c  = first ? 0.0f : cstate[row * 64 + n];
        hf = first ? 0.0f : hstate[row * 64 + n];
        ((unsigned short*)hbuf[0])[n] = f2bf(hf);
    }
    __syncthreads();

    const float* px = xg + (size_t)row * 256 + n;
    float xc = px[0];
    float xn = (Tc > 1) ? px[(size_t)BB * 256] : 0.0f;

    int cur = 0;
    for (int t = 0; t < Tc; ++t) {
#pragma unroll
        for (int j = 0; j < 8; ++j)
            asm volatile("" : "+v"(w[j].x), "+v"(w[j].y), "+v"(w[j].z), "+v"(w[j].w));

        float a = xc;
        xc = xn;
        if (t + 2 < Tc) xn = px[(size_t)(t + 2) * BB * 256];

        const uint4* hb = (const uint4*)hbuf[cur];
#pragma unroll
        for (int j = 0; j < 8; ++j) {
            uint4 hv = hb[j];
            DOT2BF(a, w[j].x, hv.x); DOT2BF(a, w[j].y, hv.y);
            DOT2BF(a, w[j].z, hv.z); DOT2BF(a, w[j].w, hv.w);
        }
        g_lds[n] = a;
        __syncthreads();

        if (n < 64) {
            float i_ = sigm(g_lds[n]);
            float f_ = sigm(g_lds[n + 64]);
            float g_ = tanh_(g_lds[n + 128]);
            float o_ = sigm(g_lds[n + 192]);
            c  = fmaf(f_, c, i_ * g_);
            hf = o_ * tanh_(c);
            unsigned short hb16 = f2bf(hf);
            ((unsigned short*)hbuf[cur ^ 1])[n] = hb16;
            ((unsigned short*)hout)[((size_t)t * BB + row) * 64 + n] = hb16;
        }
        cur ^= 1;
        __syncthreads();
    }
    if (n < 64) {
        cstate[row * 64 + n] = c;
        hstate[row * 64 + n] = hf;
    }
}

// ---------------------------------------------------------------------------
// Layer-3 input GEMM, bf16 X (r13): out[m,0..3] = sum_k X[m,k]*W[n,k] + b
// ---------------------------------------------------------------------------
__global__ __launch_bounds__(256) void gemm_xg3b(
    const __hip_bfloat16* __restrict__ X,  // [M, 64] bf16
    const float* __restrict__ W,           // [4, 64] f32
    const float* __restrict__ b1, const float* __restrict__ b2,
    float* __restrict__ out)               // [M, 4]
{
    __shared__ __align__(16) float ws4[4][64];
    __shared__ float bb[4];
    const int tid = threadIdx.x;
    {
        const int nn = tid >> 6, kk = tid & 63;
        ws4[nn][kk] = W[nn * 64 + kk];
    }
    if (tid < 4) bb[tid] = b1[tid] + b2[tid];
    __syncthreads();

    const int m = blockIdx.x * 256 + tid;
    const uint4* xr = reinterpret_cast<const uint4*>(X + (size_t)m * 64);
    float a0 = bb[0], a1 = bb[1], a2 = bb[2], a3 = bb[3];
#pragma unroll
    for (int kk = 0; kk < 8; ++kk) {       // 8 bf16 per uint4
        uint4 v = xr[kk];
        float xf[8];
        xf[0] = b2f((unsigned short)(v.x & 0xffff));
        xf[1] = b2f((unsigned short)(v.x >> 16));
        xf[2] = b2f((unsigned short)(v.y & 0xffff));
        xf[3] = b2f((unsigned short)(v.y >> 16));
        xf[4] = b2f((unsigned short)(v.z & 0xffff));
        xf[5] = b2f((unsigned short)(v.z >> 16));
        xf[6] = b2f((unsigned short)(v.w & 0xffff));
        xf[7] = b2f((unsigned short)(v.w >> 16));
#pragma unroll
        for (int j = 0; j < 8; ++j) {
            int k = kk * 8 + j;
            a0 = fmaf(xf[j], ws4[0][k], a0);
            a1 = fmaf(xf[j], ws4[1][k], a1);
            a2 = fmaf(xf[j], ws4[2][k], a2);
            a3 = fmaf(xf[j], ws4[3][k], a3);
        }
    }
    float4 o; o.x = a0; o.y = a1; o.z = a2; o.w = a3;
    *reinterpret_cast<float4*>(&out[(size_t)m * 4]) = o;
}

// ---------------------------------------------------------------------------
// Layer-3 scan: 8-deep static prefetch ring (r5, verified).
// ---------------------------------------------------------------------------
__global__ __launch_bounds__(256) void lstm_scan3(
    const float* __restrict__ xg,   // [T, B, 4]
    const float* __restrict__ Whh,  // [4, 1]
    float* __restrict__ out,        // [T, B]
    int T)
{
    const int b = threadIdx.x;
    const float w0 = Whh[0], w1 = Whh[1], w2 = Whh[2], w3 = Whh[3];
    float h = 0.0f, c = 0.0f;
    const float4* p = reinterpret_cast<const float4*>(xg) + b;

    float4 cur[8], nxt[8];
#pragma unroll
    for (int j = 0; j < 8; ++j) cur[j] = p[(size_t)j * BB];

    for (int t0 = 0; t0 < T; t0 += 8) {
#pragma unroll
        for (int j = 0; j < 8; ++j) {
            int tt = t0 + 8 + j;
            if (tt < T) nxt[j] = p[(size_t)tt * BB];
        }
#pragma unroll
        for (int j = 0; j < 8; ++j) {
            float4 g4 = cur[j];
            float gi = fmaf(h, w0, g4.x);
            float gf = fmaf(h, w1, g4.y);
            float gg = fmaf(h, w2, g4.z);
            float go = fmaf(h, w3, g4.w);
            float i_ = sigm(gi);
            float f_ = sigm(gf);
            float g_ = tanh_(gg);
            float o_ = sigm(go);
            c = fmaf(f_, c, i_ * g_);
            h = o_ * tanh_(c);
            out[(size_t)(t0 + j) * BB + b] = h;
        }
#pragma unroll
        for (int j = 0; j < 8; ++j) cur[j] = nxt[j];
    }
}

// ---------------------------------------------------------------------------
extern "C" void kernel_launch(void* const* d_in, const int* in_sizes, int n_in,
                              void* d_out, int out_size, void* d_ws, size_t ws_size,
                              hipStream_t stream) {
    const float* x    = (const float*)d_in[0];
    const float* Wih1 = (const float*)d_in[1];
    const float* Whh1 = (const float*)d_in[2];
    const float* bih1 = (const float*)d_in[3];
    const float* bhh1 = (const float*)d_in[4];
    const float* Wih2 = (const float*)d_in[5];
    const float* Whh2 = (const float*)d_in[6];
    const float* bih2 = (const float*)d_in[7];
    const float* bhh2 = (const float*)d_in[8];
    const float* Wih3 = (const float*)d_in[9];
    const float* Whh3 = (const float*)d_in[10];
    const float* bih3 = (const float*)d_in[11];
    const float* bhh3 = (const float*)d_in[12];
    float* out = (float*)d_out;

    char* ws = (char*)d_ws;
    // Workspace layout, ~187.4 MB total:
    float*          xg1c  = (float*)(ws + 0);                   // [CH,B,512] f32 = 67,108,864
    float*          xg2c  = (float*)(ws + 67108864);            // [CH,B,256] f32 = 33,554,432
    __hip_bfloat16* xb    = (__hip_bfloat16*)(ws + 100663296);  // [T,B,128] bf16 = 33,554,432
    __hip_bfloat16* h1b   = (__hip_bfloat16*)(ws + 134217728);  // [T,B,128] bf16 = 33,554,432
    __hip_bfloat16* h2bb  = (__hip_bfloat16*)(ws + 167772160);  // [T,B,64]  bf16 = 16,777,216
    float*          xg3   = (float*)(ws + 184549376);           // [T,B,4]   f32  =  2,097,152
    __hip_bfloat16* wb1   = (__hip_bfloat16*)(ws + 186646528);  // [512,128] =   131,072
    __hip_bfloat16* whb1  = (__hip_bfloat16*)(ws + 186777600);  // [512,128] =   131,072
    __hip_bfloat16* wb2   = (__hip_bfloat16*)(ws + 186908672);  // [256,128] =    65,536
    __hip_bfloat16* whb2  = (__hip_bfloat16*)(ws + 186974208);  // [256,64]  =    32,768
    float*          bias1 = (float*)(ws + 187006976);           //     2,048
    float*          bias2 = (float*)(ws + 187009024);           //     1,024
    float*          bias3 = (float*)(ws + 187010048);           //        64
    float*          st1h  = (float*)(ws + 187010112);           // [B,128] f32
    float*          st1c  = (float*)(ws + 187141184);
    float*          st2h  = (float*)(ws + 187272256);           // [B,64] f32
    float*          st2c  = (float*)(ws + 187337792);

    // ---- P0: conversions / bias prep ----
    cvt_pad<<<4096, 256, 0, stream>>>(x, xb, T_TOT * BB, 97);
    cvt_pad<<<256, 256, 0, stream>>>(Wih1, wb1, 512, 97);
    cvt_plain<<<256, 256, 0, stream>>>(Whh1, whb1, 512 * 128);
    cvt_plain<<<128, 256, 0, stream>>>(Wih2, wb2, 256 * 128);
    cvt_plain<<<64, 256, 0, stream>>>(Whh2, whb2, 256 * 64);
    addvec<<<2, 256, 0, stream>>>(bih1, bhh1, bias1, 512);
    addvec<<<1, 256, 0, stream>>>(bih2, bhh2, bias2, 256);

    // ---- Layer 1 (chunked over T) ----
    for (int c0 = 0; c0 < NCH; ++c0) {
        gemm_mfma<<<dim3(CH * BB / 128, 512 / 128), 256, 0, stream>>>(
            xb + (size_t)c0 * CH * BB * 128, wb1, bias1, xg1c, 512);
        lstm_scan1<<<BB, 256, 0, stream>>>(
            xg1c, (const unsigned int*)whb1,
            h1b + (size_t)c0 * CH * BB * 128, st1h, st1c, CH, c0 == 0);
    }
    // ---- Layer 2 (chunked over T) ----
    for (int c0 = 0; c0 < NCH; ++c0) {
        gemm_mfma<<<dim3(CH * BB / 128, 256 / 128), 256, 0, stream>>>(
            h1b + (size_t)c0 * CH * BB * 128, wb2, bias2, xg2c, 256);
        lstm_scan2<<<BB, 256, 0, stream>>>(
            xg2c, (const unsigned int*)whb2,
            h2bb + (size_t)c0 * CH * BB * 64, st2h, st2c, CH, c0 == 0);
    }
    // ---- Layer 3 ----
    gemm_xg3b<<<T_TOT * BB / 256, 256, 0, stream>>>(h2bb, Wih3, bih3, bhh3, xg3);
    lstm_scan3<<<1, 256, 0, stream>>>(xg3, Whh3, out, T_TOT);
}